// Round 1
// 83.323 us; speedup vs baseline: 1.0315x; 1.0315x over previous
//
#include <hip/hip_runtime.h>
#include <float.h>
#include <math.h>

#define CCH 256       // channels
#define PIX 4096      // 64*64 feature pixels
#define LREF 64       // number of reference feats
#define IMGSZ 1024
#define THRESH 0.65f

typedef unsigned long long u64;

// monotone bijection fp32 -> u32 (order-preserving, no NaNs in data)
__device__ __forceinline__ unsigned mono32(float v) {
    unsigned u = __float_as_uint(v);
    return u ^ ((unsigned)((int)u >> 31) | 0x80000000u);
}
__device__ __forceinline__ float unmono32(unsigned m) {
    unsigned u = (m & 0x80000000u) ? (m ^ 0x80000000u) : ~m;
    return __uint_as_float(u);
}
// lerp that is EXACT at w==0 (-> a) and w==1 (-> b)
__device__ __forceinline__ float lrp(float a, float b, float w) {
    return fmaf(w, b, fmaf(-w, a, a));
}

// ---------- Fused: sim (norm + dot) -> LDS patch -> per-cell fg/bg keys ----------
// grid (gy=16, lg=16, z=2), 256 threads. Block covers 4 l's x 8 cells of row gy.
// NO WORKSPACE: intermediates live inside the output buffer. Per l, the 768-float
// pts slot [l*768 .. l*768+768) temporarily holds (as u64, 384 slots):
//   [0..256)  : fg keys, one per grid cell (gy*16+cxg)
//   [256..288): bg partial min keys, one per (gy,z) block  (32 total)
// k_final block l reads only its own slot before overwriting it -> race-free.
__global__ __launch_bounds__(256) void k_fused(const float* __restrict__ emb,
                                               const float* __restrict__ ref,
                                               float* __restrict__ out) {
    const int gy = blockIdx.x;    // 0..15
    const int lg = blockIdx.y;    // 0..15 -> l = 4*lg + l2
    const int z  = blockIdx.z;    // 0..1  -> cells 8z..8z+7
    const int t  = threadIdx.x;

    __shared__ float patch[4][6][34];   // [l2][src row 4gy-1.. (clamped)][src col 32z-1.. (clamped)]

    const int jb = 32 * z - 1;          // src col of patch j=0
    const float* r0 = ref + (size_t)(lg * 4 + 0) * CCH;   // wave-uniform -> s_load
    const float* r1 = ref + (size_t)(lg * 4 + 1) * CCH;
    const float* r2 = ref + (size_t)(lg * 4 + 2) * CCH;
    const float* r3 = ref + (size_t)(lg * 4 + 3) * CCH;

    if (t < 204) {                       // 6 rows x 34 cols
        int ri = t / 34, j = t % 34;
        int rr = min(max(4 * gy - 1 + ri, 0), 63);
        int cc = min(max(jb + j, 0), 63);
        const float* ep = emb + rr * 64 + cc;
        float a0 = 0.f, a1 = 0.f, a2 = 0.f, a3 = 0.f, nn = 0.f;
#pragma unroll 8
        for (int c = 0; c < CCH; ++c) {
            float v = ep[(size_t)c * PIX];
            nn = fmaf(v, v, nn);
            a0 = fmaf(r0[c], v, a0);
            a1 = fmaf(r1[c], v, a1);
            a2 = fmaf(r2[c], v, a2);
            a3 = fmaf(r3[c], v, a3);
        }
        float inv = 1.0f / sqrtf(nn);
        patch[0][ri][j] = a0 * inv;
        patch[1][ri][j] = a1 * inv;
        patch[2][ri][j] = a2 * inv;
        patch[3][ri][j] = a3 * inv;
    }
    __syncthreads();

    const int dx  = t & 63;
    const int l2  = t >> 6;             // wave index == l2
    const int l   = lg * 4 + l2;
    const bool gy0 = (gy == 0), gy15 = (gy == 15);

    u64* ob = (u64*)out + (size_t)l * 384;   // this l's intermediate slot
    u64 bgrun = 0xFFFFFFFFFFFFFFFFULL;       // running bg min across this wave's 8 cells

    for (int ci = 0; ci < 8; ++ci) {
        int cxg = 8 * z + ci;           // global cell col
        int x = cxg * 64 + dx;
        // sample_f = (x+0.5)/16 - 0.5, clamped (== jax.image.resize edge rule)
        float tx = fminf(fmaxf((float)x * 0.0625f - 0.46875f, 0.f), 63.f);
        int x0 = (int)tx; float wx = tx - (float)x0; int x1 = min(x0 + 1, 63);
        int j0 = x0 - jb, j1 = x1 - jb;

        u64 fg = 0ULL;
#pragma unroll
        for (int s = 0; s < 4; ++s) {
            float hA = lrp(patch[l2][s    ][j0], patch[l2][s    ][j1], wx);
            float hB = lrp(patch[l2][s + 1][j0], patch[l2][s + 1][j1], wx);
            float hC = lrp(patch[l2][s + 2][j0], patch[l2][s + 2][j1], wx);
            bool eB = gy0  && (s == 0);  // seg1 wy clamps -> all == src row 0
            bool eT = gy15 && (s == 3);  // seg2 wy clamps -> all == src row 63
            float w0 = eB ? 1.0f : 0.53125f;   // seg1 k=0
            float w1 = eB ? 1.0f : 0.96875f;   // seg1 k=7
            float w2 = eT ? 0.0f : 0.03125f;   // seg2 k=8
            float w3 = eT ? 0.0f : 0.46875f;   // seg2 k=15
            float e0 = lrp(hA, hB, w0);
            float e1 = lrp(hA, hB, w1);
            float e2 = lrp(hB, hC, w2);
            float e3 = lrp(hB, hC, w3);
            // bg: min, first-k on ties
            float bv = e0; int bk = 0;
            if (e1 < bv) { bv = e1; bk = 7; }
            if (e2 < bv) { bv = e2; bk = 8; }
            if (e3 < bv) { bv = e3; bk = 15; }
            u64 key = ((u64)mono32(bv) << 32)
                    | (unsigned)(((gy * 64 + s * 16 + bk) << 10) + x);
            if (key < bgrun) bgrun = key;
            // fg: rare path (skipped wave-wide when nothing exceeds THRESH)
            if (__ballot(fmaxf(fmaxf(e0, e1), fmaxf(e2, e3)) > THRESH)) {
                float gv = e0; int gk = 0;
                if (e1 > gv) { gv = e1; gk = 7; }
                if (e2 > gv) { gv = e2; gk = 8; }
                if (e3 > gv) { gv = e3; gk = 15; }
                int fi = (s * 16 + gk) * 64 + dx;   // in-cell flat idx
                u64 fk = (gv > THRESH)
                       ? (((u64)mono32(gv) << 32) | (unsigned)(4095 - fi))
                       : 0ULL;
                if (fk > fg) fg = fk;   // keys unique across strips -> first-idx safe
            }
        }
        // fg wave reduction over 64 dx lanes (per cell)
        if (__ballot(fg != 0ULL)) {
#pragma unroll
            for (int off = 32; off > 0; off >>= 1) {
                u64 o = __shfl_xor(fg, off);
                if (o > fg) fg = o;     // max val, tie -> min fi
            }
        }
        if (dx == 0) ob[gy * 16 + cxg] = fg;
    }
    // bg: one wave reduction for all 8 cells (min is associative -> same key
    // as the old per-cell-reduce-then-global-min; keys are unique)
#pragma unroll
    for (int off = 32; off > 0; off >>= 1) {
        u64 o = __shfl_xor(bgrun, off);
        if (o < bgrun) bgrun = o;
    }
    if (dx == 0) ob[256 + gy * 2 + z] = bgrun;
}

// ---------- K2: per l: assemble pts, stable rank by score desc, bg key-min ----------
// Reads this l's intermediate slot from out, then overwrites it with final pts.
// All global reads complete before the __syncthreads(); all writes after -> safe.
__global__ __launch_bounds__(256) void k_final(float* __restrict__ out) {
    const int l = blockIdx.x;
    const int t = threadIdx.x;   // grid cell g = gy*16+gx

    __shared__ float sc[256];

    const u64* base = (const u64*)out + (size_t)l * 384;
    u64 key = base[t];                                   // fg key for cell t
    u64 bg  = (t < 32) ? base[256 + t] : 0xFFFFFFFFFFFFFFFFULL;  // bg partials

    bool valid = key != 0ULL;
    float val = unmono32((unsigned)(key >> 32));
    int   fi  = 4095 - (int)(key & 0xFFFFFFFFULL);
    int gy = t >> 4, gx = t & 15;
    float xx = valid ? (float)(gx * 64 + (fi & 63)) : 0.f;
    float yy = valid ? (float)(gy * 64 + (fi >> 6)) : 0.f;
    float ss = valid ? val : 0.f;

    sc[t] = ss;
    __syncthreads();            // all reads of base[] done before any write below

    // stable descending rank (ties -> lower cell index first, == argsort)
    int rank = 0;
    for (int j = 0; j < 256; ++j) {
        float o = sc[j];
        rank += (o > ss) || (o == ss && j < t);
    }

    // bg: min across the 32 partials (live in wave 0 lanes 0..31; other lanes ~0)
#pragma unroll
    for (int off = 32; off > 0; off >>= 1) {
        u64 o = __shfl_xor(bg, off);
        if (o < bg) bg = o;
    }

    float* p = out + (size_t)(l * 256 + rank) * 3;
    p[0] = xx; p[1] = yy; p[2] = ss;

    if (t == 0) {
        unsigned idx = (unsigned)(bg & 0xFFFFFFFFULL);
        out[(size_t)LREF * 256 * 3 + l * 2 + 0] = (float)(idx & (IMGSZ - 1));  // x
        out[(size_t)LREF * 256 * 3 + l * 2 + 1] = (float)(idx >> 10);          // y
    }
}

extern "C" void kernel_launch(void* const* d_in, const int* in_sizes, int n_in,
                              void* d_out, int out_size, void* d_ws, size_t ws_size,
                              hipStream_t stream) {
    (void)d_ws; (void)ws_size;                  // workspace unused: avoids its re-poison cost
    const float* emb = (const float*)d_in[0];   // (1,256,64,64)
    const float* ref = (const float*)d_in[1];   // (64,1,256)
    float* out = (float*)d_out;                 // 49152 (pts) + 128 (bg)

    k_fused<<<dim3(16, 16, 2), dim3(256), 0, stream>>>(emb, ref, out);
    k_final<<<dim3(LREF), dim3(256), 0, stream>>>(out);
}